// Round 9
// baseline (336.025 us; speedup 1.0000x reference)
//
#include <hip/hip_runtime.h>

// SparseGrid trilinear interpolation (Plenoxels-style).
// reso = 128^3, data_dim = 28, npts = 2,000,000.
// Mapping: p = pt*64 + 63.5 (R=1, C=0, gsz=128 — exact in f32).
//
// Round-9: LDS BRICK STAGING. R8 showed the interp kernel is scatter-
// issue-bound (FETCH 148 MB, 438 GB/s, VALU 12% — TA pipe saturated by
// 8x wave64 scattered 16 B gathers). Move the scatter to LDS: one block
// per 8^3-cell brick (4096 buckets), stage the 9^3-row halo (81.6 KB,
// exactly 2 blocks/CU) with coalesced loads, then all corner reads are
// ds_read_b128. Rows with link<0 are zeroed at staging time. Sort = R7's
// count/scan/scatter at 4096 buckets (ws 32.03 MB, proven available).
// Bucket start in interp = cursor[b] - cnt[b] (cursor is end post-scatter).

#define RES 128
#define DD  28     // 9*3+1 floats per row
#define NBKT 4096  // 16^3 bricks of 8^3 cells
#define NROWS 729  // 9^3 halo rows per brick
#define BTPB 512   // interp threads: 8 waves, 73 points/iter

#define CNT_TPB 256
#define CNT_PPT 16
#define CNT_PTS (CNT_TPB * CNT_PPT)

#define SC_TPB 256
#define SC_PPT 8
#define SC_PTS (SC_TPB * SC_PPT)

typedef float vf4 __attribute__((ext_vector_type(4)));

struct __align__(16) PtRec { float x, y, z; int p; };

__device__ __forceinline__ void cell_of(float x, float y, float z,
                                        int& lx, int& ly, int& lz) {
    float px = fminf(fmaxf(x * 64.0f + 63.5f, 0.0f), 127.0f);
    float py = fminf(fmaxf(y * 64.0f + 63.5f, 0.0f), 127.0f);
    float pz = fminf(fmaxf(z * 64.0f + 63.5f, 0.0f), 127.0f);
    lx = min((int)px, RES - 2);
    ly = min((int)py, RES - 2);
    lz = min((int)pz, RES - 2);
}

__device__ __forceinline__ int bucket_of(int lx, int ly, int lz) {
    return ((lx >> 3) << 8) | ((ly >> 3) << 4) | (lz >> 3);
}

// K1: per-bucket histogram.
__global__ __launch_bounds__(CNT_TPB) void count_kernel(
    const float* __restrict__ points, int npts, int* __restrict__ cnt)
{
    __shared__ int h[NBKT];
    for (int i = threadIdx.x; i < NBKT; i += CNT_TPB) h[i] = 0;
    __syncthreads();
    const int p0 = blockIdx.x * CNT_PTS;
#pragma unroll
    for (int k = 0; k < CNT_PPT; ++k) {
        int p = p0 + k * CNT_TPB + threadIdx.x;
        if (p < npts) {
            int lx, ly, lz;
            cell_of(points[p * 3], points[p * 3 + 1], points[p * 3 + 2], lx, ly, lz);
            atomicAdd(&h[bucket_of(lx, ly, lz)], 1);
        }
    }
    __syncthreads();
    for (int i = threadIdx.x; i < NBKT; i += CNT_TPB)
        if (h[i]) atomicAdd(&cnt[i], h[i]);
}

// K2: exclusive scan of 4096 counts.
__global__ __launch_bounds__(1024) void scan_kernel(
    const int* __restrict__ cnt, int* __restrict__ cursor)
{
    __shared__ int part[1024];
    const int t = threadIdx.x;
    int a = cnt[4 * t], b = cnt[4 * t + 1], c = cnt[4 * t + 2], d = cnt[4 * t + 3];
    int sum = a + b + c + d;
    part[t] = sum;
    __syncthreads();
    for (int off = 1; off < 1024; off <<= 1) {
        int v = (t >= off) ? part[t - off] : 0;
        __syncthreads();
        part[t] += v;
        __syncthreads();
    }
    int excl = part[t] - sum;
    cursor[4 * t]     = excl;
    cursor[4 * t + 1] = excl + a;
    cursor[4 * t + 2] = excl + a + b;
    cursor[4 * t + 3] = excl + a + b + c;
}

// K3: scatter packed records grouped by bucket.
__global__ __launch_bounds__(SC_TPB) void scatter_kernel(
    const float* __restrict__ points, int npts, int* __restrict__ cursor,
    PtRec* __restrict__ recs)
{
    __shared__ int h[NBKT];
    __shared__ int base[NBKT];
    for (int i = threadIdx.x; i < NBKT; i += SC_TPB) h[i] = 0;
    __syncthreads();

    const int p0 = blockIdx.x * SC_PTS;
    float xs[SC_PPT], ys[SC_PPT], zs[SC_PPT];
    int   sb[SC_PPT], rk[SC_PPT];
#pragma unroll
    for (int k = 0; k < SC_PPT; ++k) {
        int p = p0 + k * SC_TPB + threadIdx.x;
        sb[k] = -1;
        if (p < npts) {
            xs[k] = points[p * 3];
            ys[k] = points[p * 3 + 1];
            zs[k] = points[p * 3 + 2];
            int lx, ly, lz;
            cell_of(xs[k], ys[k], zs[k], lx, ly, lz);
            sb[k] = bucket_of(lx, ly, lz);
            rk[k] = atomicAdd(&h[sb[k]], 1);
        }
    }
    __syncthreads();
    for (int i = threadIdx.x; i < NBKT; i += SC_TPB) {
        int c = h[i];
        base[i] = c ? atomicAdd(&cursor[i], c) : 0;
    }
    __syncthreads();
#pragma unroll
    for (int k = 0; k < SC_PPT; ++k) {
        if (sb[k] >= 0) {
            int p = p0 + k * SC_TPB + threadIdx.x;
            PtRec r; r.x = xs[k]; r.y = ys[k]; r.z = zs[k]; r.p = p;
            recs[base[sb[k]] + rk[k]] = r;
        }
    }
}

// K4: one block per brick; stage halo into LDS, interp from LDS.
__global__ __launch_bounds__(BTPB) void trilerp_brick_kernel(
    const float* __restrict__ data,
    const int*   __restrict__ links,
    const PtRec* __restrict__ recs,
    const int*   __restrict__ cnt,
    const int*   __restrict__ cursor,   // post-scatter: end offsets
    float*       __restrict__ out)
{
    // 81,648 B: exactly 2 blocks per 160 KiB CU. Pitch 28 words: row r
    // starts at byte 112r (16B-aligned); bank start (28r)%32 cycles over
    // 8 distinct values -> spread for cross-point ds_read_b128.
    __shared__ __align__(16) float sd[NROWS * DD];

    // XCD-chunked bijective swizzle (4096 % 8 == 0): XCD k owns a
    // contiguous, spatially-local run of bricks -> halo overlap L2-hits.
    const int orig = blockIdx.x;
    const int b = (orig & 7) * (NBKT / 8) + (orig >> 3);

    const int bx = (b >> 8) & 15, by = (b >> 4) & 15, bz = b & 15;
    const int ox = bx << 3, oy = by << 3, oz = bz << 3;

    const int tid = threadIdx.x;

    // ---- stage: 729 rows x 7 float4, coalesced; zero rows with link<0.
    for (int s = tid; s < NROWS * 7; s += BTPB) {
        const int r = s / 7, j = s % 7;
        const int dx = r / 81, rem = r % 81, dy = rem / 9, dz = rem % 9;
        const int gx = min(ox + dx, 127);
        const int gy = min(oy + dy, 127);
        const int gz = min(oz + dz, 127);
        const int link = links[(gx * RES + gy) * RES + gz];
        vf4 v = (vf4)(0.0f);
        if (link >= 0)
            v = *(const vf4*)(data + (long)link * DD + j * 4);
        *(vf4*)&sd[r * DD + j * 4] = v;
    }
    __syncthreads();

    // ---- compute: 73 points per iteration (7 lanes per point).
    const int cb  = cnt[b];
    const int beg = cursor[b] - cb;
    const int j   = tid % 7;
    const int pl  = tid / 7;          // 0..73 (73 -> idle lane)

    for (int s0 = 0; s0 < cb; s0 += 73) {
        const int li = s0 + pl;
        if (pl < 73 && li < cb) {
            const PtRec rec = recs[beg + li];   // 7 lanes same addr: broadcast

            float px = fminf(fmaxf(rec.x * 64.0f + 63.5f, 0.0f), 127.0f);
            float py = fminf(fmaxf(rec.y * 64.0f + 63.5f, 0.0f), 127.0f);
            float pz = fminf(fmaxf(rec.z * 64.0f + 63.5f, 0.0f), 127.0f);
            int lx = min((int)px, RES - 2);
            int ly = min((int)py, RES - 2);
            int lz = min((int)pz, RES - 2);

            float wbx = px - (float)lx, wby = py - (float)ly, wbz = pz - (float)lz;
            float wax = 1.0f - wbx,     way = 1.0f - wby,     waz = 1.0f - wbz;

            float w[8];
            w[0] = wax * way * waz;
            w[1] = wax * way * wbz;
            w[2] = wax * wby * waz;
            w[3] = wax * wby * wbz;
            w[4] = wbx * way * waz;
            w[5] = wbx * way * wbz;
            w[6] = wbx * wby * waz;
            w[7] = wbx * wby * wbz;

            const int r0 = ((lx - ox) * 9 + (ly - oy)) * 9 + (lz - oz);
            const int offs[8] = {0, 1, 9, 10, 81, 82, 90, 91};

            vf4 acc = (vf4)(0.0f);
#pragma unroll
            for (int i = 0; i < 8; ++i) {
                vf4 v = *(const vf4*)&sd[(r0 + offs[i]) * DD + j * 4];
                acc += w[i] * v;
            }

            vf4* o = (vf4*)(out + (long)rec.p * DD + (long)j * 4);
            __builtin_nontemporal_store(acc, o);
        }
    }
}

// Fallback (no scratch): direct order, 7 threads/point.
__global__ __launch_bounds__(448) void trilerp_direct_kernel(
    const float* __restrict__ data,
    const float* __restrict__ points,
    const int*   __restrict__ links,
    float*       __restrict__ out,
    int npts)
{
    const int tid = threadIdx.x;
    const int j   = tid % 7;
    const int pl  = tid / 7;
    const int p   = blockIdx.x * 64 + pl;
    if (p >= npts) return;

    float px = fminf(fmaxf(points[p * 3 + 0] * 64.0f + 63.5f, 0.0f), 127.0f);
    float py = fminf(fmaxf(points[p * 3 + 1] * 64.0f + 63.5f, 0.0f), 127.0f);
    float pz = fminf(fmaxf(points[p * 3 + 2] * 64.0f + 63.5f, 0.0f), 127.0f);
    int lx = min((int)px, RES - 2);
    int ly = min((int)py, RES - 2);
    int lz = min((int)pz, RES - 2);
    float wbx = px - (float)lx, wby = py - (float)ly, wbz = pz - (float)lz;
    float wax = 1.0f - wbx,     way = 1.0f - wby,     waz = 1.0f - wbz;
    const int base = (lx * RES + ly) * RES + lz;
    int ls[8];
    ls[0] = links[base];
    ls[1] = links[base + 1];
    ls[2] = links[base + RES];
    ls[3] = links[base + RES + 1];
    ls[4] = links[base + RES * RES];
    ls[5] = links[base + RES * RES + 1];
    ls[6] = links[base + RES * RES + RES];
    ls[7] = links[base + RES * RES + RES + 1];
    float w[8];
    w[0] = wax * way * waz; w[1] = wax * way * wbz;
    w[2] = wax * wby * waz; w[3] = wax * wby * wbz;
    w[4] = wbx * way * waz; w[5] = wbx * way * wbz;
    w[6] = wbx * wby * waz; w[7] = wbx * wby * wbz;
    vf4 v[8];
#pragma unroll
    for (int i = 0; i < 8; ++i) {
        const int li = ls[i] >= 0 ? ls[i] : 0;
        v[i] = *(const vf4*)(data + (long)li * DD + j * 4);
    }
    vf4 acc = (vf4)(0.0f);
#pragma unroll
    for (int i = 0; i < 8; ++i) {
        const float wi = ls[i] >= 0 ? w[i] : 0.0f;
        acc += wi * v[i];
    }
    vf4* o = (vf4*)(out + (long)p * DD + (long)j * 4);
    __builtin_nontemporal_store(acc, o);
}

extern "C" void kernel_launch(void* const* d_in, const int* in_sizes, int n_in,
                              void* d_out, int out_size, void* d_ws, size_t ws_size,
                              hipStream_t stream) {
    const float* data   = (const float*)d_in[0];
    const float* points = (const float*)d_in[1];
    const int*   links  = (const int*)d_in[2];
    float*       out    = (float*)d_out;

    int npts = in_sizes[1] / 3;

    const size_t need = (size_t)2 * NBKT * sizeof(int) + (size_t)npts * sizeof(PtRec);
    if (ws_size < need) {
        const int grid = (npts + 63) / 64;
        hipLaunchKernelGGL(trilerp_direct_kernel, dim3(grid), dim3(448), 0, stream,
                           data, points, links, out, npts);
        return;
    }

    int*   cnt    = (int*)d_ws;               // [NBKT]
    int*   cursor = cnt + NBKT;               // [NBKT]
    PtRec* recs   = (PtRec*)(cursor + NBKT);  // [npts], 32 KB offset -> 16B aligned

    hipMemsetAsync(cnt, 0, NBKT * sizeof(int), stream);

    const int nbc = (npts + CNT_PTS - 1) / CNT_PTS;
    const int nbs = (npts + SC_PTS - 1) / SC_PTS;
    hipLaunchKernelGGL(count_kernel,   dim3(nbc), dim3(CNT_TPB), 0, stream, points, npts, cnt);
    hipLaunchKernelGGL(scan_kernel,    dim3(1),   dim3(1024),    0, stream, cnt, cursor);
    hipLaunchKernelGGL(scatter_kernel, dim3(nbs), dim3(SC_TPB),  0, stream, points, npts, cursor, recs);

    hipLaunchKernelGGL(trilerp_brick_kernel, dim3(NBKT), dim3(BTPB), 0, stream,
                       data, links, recs, cnt, cursor, out);
}

// Round 10
// 309.363 us; speedup vs baseline: 1.0862x; 1.0862x over previous
//
#include <hip/hip_runtime.h>

// SparseGrid trilinear interpolation (Plenoxels-style).
// reso = 128^3, data_dim = 28, npts = 2,000,000.
// Mapping: p = pt*64 + 63.5 (R=1, C=0, gsz=128 — exact in f32).
//
// Round-10: R9 structure, two changes:
// (a) brick kernel's scattered out store loses the NT hint. R8 (TA
//     gathers) and R9 (LDS gathers) cost the same -> bottleneck is in
//     the shared parts; prime suspect is 2M scattered nt stores of
//     112 B partial lines (nt defeats L2 write-merging -> memory-side
//     RMW). Let L2 absorb them.
// (b) count kernel PPT 16->32: halves merge-atomic volume and block
//     count (sort-side cost, disjoint from interp experiment).

#define RES 128
#define DD  28     // 9*3+1 floats per row
#define NBKT 4096  // 16^3 bricks of 8^3 cells
#define NROWS 729  // 9^3 halo rows per brick
#define BTPB 512   // interp threads: 8 waves, 73 points/iter

#define CNT_TPB 256
#define CNT_PPT 32
#define CNT_PTS (CNT_TPB * CNT_PPT)

#define SC_TPB 256
#define SC_PPT 8
#define SC_PTS (SC_TPB * SC_PPT)

typedef float vf4 __attribute__((ext_vector_type(4)));

struct __align__(16) PtRec { float x, y, z; int p; };

__device__ __forceinline__ void cell_of(float x, float y, float z,
                                        int& lx, int& ly, int& lz) {
    float px = fminf(fmaxf(x * 64.0f + 63.5f, 0.0f), 127.0f);
    float py = fminf(fmaxf(y * 64.0f + 63.5f, 0.0f), 127.0f);
    float pz = fminf(fmaxf(z * 64.0f + 63.5f, 0.0f), 127.0f);
    lx = min((int)px, RES - 2);
    ly = min((int)py, RES - 2);
    lz = min((int)pz, RES - 2);
}

__device__ __forceinline__ int bucket_of(int lx, int ly, int lz) {
    return ((lx >> 3) << 8) | ((ly >> 3) << 4) | (lz >> 3);
}

// K1: per-bucket histogram.
__global__ __launch_bounds__(CNT_TPB) void count_kernel(
    const float* __restrict__ points, int npts, int* __restrict__ cnt)
{
    __shared__ int h[NBKT];
    for (int i = threadIdx.x; i < NBKT; i += CNT_TPB) h[i] = 0;
    __syncthreads();
    const int p0 = blockIdx.x * CNT_PTS;
#pragma unroll 4
    for (int k = 0; k < CNT_PPT; ++k) {
        int p = p0 + k * CNT_TPB + threadIdx.x;
        if (p < npts) {
            int lx, ly, lz;
            cell_of(points[p * 3], points[p * 3 + 1], points[p * 3 + 2], lx, ly, lz);
            atomicAdd(&h[bucket_of(lx, ly, lz)], 1);
        }
    }
    __syncthreads();
    for (int i = threadIdx.x; i < NBKT; i += CNT_TPB)
        if (h[i]) atomicAdd(&cnt[i], h[i]);
}

// K2: exclusive scan of 4096 counts.
__global__ __launch_bounds__(1024) void scan_kernel(
    const int* __restrict__ cnt, int* __restrict__ cursor)
{
    __shared__ int part[1024];
    const int t = threadIdx.x;
    int a = cnt[4 * t], b = cnt[4 * t + 1], c = cnt[4 * t + 2], d = cnt[4 * t + 3];
    int sum = a + b + c + d;
    part[t] = sum;
    __syncthreads();
    for (int off = 1; off < 1024; off <<= 1) {
        int v = (t >= off) ? part[t - off] : 0;
        __syncthreads();
        part[t] += v;
        __syncthreads();
    }
    int excl = part[t] - sum;
    cursor[4 * t]     = excl;
    cursor[4 * t + 1] = excl + a;
    cursor[4 * t + 2] = excl + a + b;
    cursor[4 * t + 3] = excl + a + b + c;
}

// K3: scatter packed records grouped by bucket.
__global__ __launch_bounds__(SC_TPB) void scatter_kernel(
    const float* __restrict__ points, int npts, int* __restrict__ cursor,
    PtRec* __restrict__ recs)
{
    __shared__ int h[NBKT];
    __shared__ int base[NBKT];
    for (int i = threadIdx.x; i < NBKT; i += SC_TPB) h[i] = 0;
    __syncthreads();

    const int p0 = blockIdx.x * SC_PTS;
    float xs[SC_PPT], ys[SC_PPT], zs[SC_PPT];
    int   sb[SC_PPT], rk[SC_PPT];
#pragma unroll
    for (int k = 0; k < SC_PPT; ++k) {
        int p = p0 + k * SC_TPB + threadIdx.x;
        sb[k] = -1;
        if (p < npts) {
            xs[k] = points[p * 3];
            ys[k] = points[p * 3 + 1];
            zs[k] = points[p * 3 + 2];
            int lx, ly, lz;
            cell_of(xs[k], ys[k], zs[k], lx, ly, lz);
            sb[k] = bucket_of(lx, ly, lz);
            rk[k] = atomicAdd(&h[sb[k]], 1);
        }
    }
    __syncthreads();
    for (int i = threadIdx.x; i < NBKT; i += SC_TPB) {
        int c = h[i];
        base[i] = c ? atomicAdd(&cursor[i], c) : 0;
    }
    __syncthreads();
#pragma unroll
    for (int k = 0; k < SC_PPT; ++k) {
        if (sb[k] >= 0) {
            int p = p0 + k * SC_TPB + threadIdx.x;
            PtRec r; r.x = xs[k]; r.y = ys[k]; r.z = zs[k]; r.p = p;
            recs[base[sb[k]] + rk[k]] = r;
        }
    }
}

// K4: one block per brick; stage halo into LDS, interp from LDS.
__global__ __launch_bounds__(BTPB) void trilerp_brick_kernel(
    const float* __restrict__ data,
    const int*   __restrict__ links,
    const PtRec* __restrict__ recs,
    const int*   __restrict__ cnt,
    const int*   __restrict__ cursor,   // post-scatter: end offsets
    float*       __restrict__ out)
{
    __shared__ __align__(16) float sd[NROWS * DD];  // 81,648 B: 2 blocks/CU

    // XCD-chunked bijective swizzle (4096 % 8 == 0).
    const int orig = blockIdx.x;
    const int b = (orig & 7) * (NBKT / 8) + (orig >> 3);

    const int bx = (b >> 8) & 15, by = (b >> 4) & 15, bz = b & 15;
    const int ox = bx << 3, oy = by << 3, oz = bz << 3;

    const int tid = threadIdx.x;

    // ---- stage: 729 rows x 7 float4, coalesced; zero rows with link<0.
    for (int s = tid; s < NROWS * 7; s += BTPB) {
        const int r = s / 7, j = s % 7;
        const int dx = r / 81, rem = r % 81, dy = rem / 9, dz = rem % 9;
        const int gx = min(ox + dx, 127);
        const int gy = min(oy + dy, 127);
        const int gz = min(oz + dz, 127);
        const int link = links[(gx * RES + gy) * RES + gz];
        vf4 v = (vf4)(0.0f);
        if (link >= 0)
            v = *(const vf4*)(data + (long)link * DD + j * 4);
        *(vf4*)&sd[r * DD + j * 4] = v;
    }
    __syncthreads();

    // ---- compute: 73 points per iteration (7 lanes per point).
    const int cb  = cnt[b];
    const int beg = cursor[b] - cb;
    const int j   = tid % 7;
    const int pl  = tid / 7;          // 0..73 (73 -> idle lane)

    for (int s0 = 0; s0 < cb; s0 += 73) {
        const int li = s0 + pl;
        if (pl < 73 && li < cb) {
            const PtRec rec = recs[beg + li];   // 7 lanes same addr: broadcast

            float px = fminf(fmaxf(rec.x * 64.0f + 63.5f, 0.0f), 127.0f);
            float py = fminf(fmaxf(rec.y * 64.0f + 63.5f, 0.0f), 127.0f);
            float pz = fminf(fmaxf(rec.z * 64.0f + 63.5f, 0.0f), 127.0f);
            int lx = min((int)px, RES - 2);
            int ly = min((int)py, RES - 2);
            int lz = min((int)pz, RES - 2);

            float wbx = px - (float)lx, wby = py - (float)ly, wbz = pz - (float)lz;
            float wax = 1.0f - wbx,     way = 1.0f - wby,     waz = 1.0f - wbz;

            float w[8];
            w[0] = wax * way * waz;
            w[1] = wax * way * wbz;
            w[2] = wax * wby * waz;
            w[3] = wax * wby * wbz;
            w[4] = wbx * way * waz;
            w[5] = wbx * way * wbz;
            w[6] = wbx * wby * waz;
            w[7] = wbx * wby * wbz;

            const int r0 = ((lx - ox) * 9 + (ly - oy)) * 9 + (lz - oz);
            const int offs[8] = {0, 1, 9, 10, 81, 82, 90, 91};

            vf4 acc = (vf4)(0.0f);
#pragma unroll
            for (int i = 0; i < 8; ++i) {
                vf4 v = *(const vf4*)&sd[(r0 + offs[i]) * DD + j * 4];
                acc += w[i] * v;
            }

            // Plain store (R10 change): scattered partial-line writes go
            // through L2 so the cache can merge/retire them lazily.
            vf4* o = (vf4*)(out + (long)rec.p * DD + (long)j * 4);
            *o = acc;
        }
    }
}

// Fallback (no scratch): direct order, 7 threads/point.
__global__ __launch_bounds__(448) void trilerp_direct_kernel(
    const float* __restrict__ data,
    const float* __restrict__ points,
    const int*   __restrict__ links,
    float*       __restrict__ out,
    int npts)
{
    const int tid = threadIdx.x;
    const int j   = tid % 7;
    const int pl  = tid / 7;
    const int p   = blockIdx.x * 64 + pl;
    if (p >= npts) return;

    float px = fminf(fmaxf(points[p * 3 + 0] * 64.0f + 63.5f, 0.0f), 127.0f);
    float py = fminf(fmaxf(points[p * 3 + 1] * 64.0f + 63.5f, 0.0f), 127.0f);
    float pz = fminf(fmaxf(points[p * 3 + 2] * 64.0f + 63.5f, 0.0f), 127.0f);
    int lx = min((int)px, RES - 2);
    int ly = min((int)py, RES - 2);
    int lz = min((int)pz, RES - 2);
    float wbx = px - (float)lx, wby = py - (float)ly, wbz = pz - (float)lz;
    float wax = 1.0f - wbx,     way = 1.0f - wby,     waz = 1.0f - wbz;
    const int base = (lx * RES + ly) * RES + lz;
    int ls[8];
    ls[0] = links[base];
    ls[1] = links[base + 1];
    ls[2] = links[base + RES];
    ls[3] = links[base + RES + 1];
    ls[4] = links[base + RES * RES];
    ls[5] = links[base + RES * RES + 1];
    ls[6] = links[base + RES * RES + RES];
    ls[7] = links[base + RES * RES + RES + 1];
    float w[8];
    w[0] = wax * way * waz; w[1] = wax * way * wbz;
    w[2] = wax * wby * waz; w[3] = wax * wby * wbz;
    w[4] = wbx * way * waz; w[5] = wbx * way * wbz;
    w[6] = wbx * wby * waz; w[7] = wbx * wby * wbz;
    vf4 v[8];
#pragma unroll
    for (int i = 0; i < 8; ++i) {
        const int li = ls[i] >= 0 ? ls[i] : 0;
        v[i] = *(const vf4*)(data + (long)li * DD + j * 4);
    }
    vf4 acc = (vf4)(0.0f);
#pragma unroll
    for (int i = 0; i < 8; ++i) {
        const float wi = ls[i] >= 0 ? w[i] : 0.0f;
        acc += wi * v[i];
    }
    vf4* o = (vf4*)(out + (long)p * DD + (long)j * 4);
    *o = acc;
}

extern "C" void kernel_launch(void* const* d_in, const int* in_sizes, int n_in,
                              void* d_out, int out_size, void* d_ws, size_t ws_size,
                              hipStream_t stream) {
    const float* data   = (const float*)d_in[0];
    const float* points = (const float*)d_in[1];
    const int*   links  = (const int*)d_in[2];
    float*       out    = (float*)d_out;

    int npts = in_sizes[1] / 3;

    const size_t need = (size_t)2 * NBKT * sizeof(int) + (size_t)npts * sizeof(PtRec);
    if (ws_size < need) {
        const int grid = (npts + 63) / 64;
        hipLaunchKernelGGL(trilerp_direct_kernel, dim3(grid), dim3(448), 0, stream,
                           data, points, links, out, npts);
        return;
    }

    int*   cnt    = (int*)d_ws;               // [NBKT]
    int*   cursor = cnt + NBKT;               // [NBKT]
    PtRec* recs   = (PtRec*)(cursor + NBKT);  // [npts], 32 KB offset -> 16B aligned

    hipMemsetAsync(cnt, 0, NBKT * sizeof(int), stream);

    const int nbc = (npts + CNT_PTS - 1) / CNT_PTS;
    const int nbs = (npts + SC_PTS - 1) / SC_PTS;
    hipLaunchKernelGGL(count_kernel,   dim3(nbc), dim3(CNT_TPB), 0, stream, points, npts, cnt);
    hipLaunchKernelGGL(scan_kernel,    dim3(1),   dim3(1024),    0, stream, cnt, cursor);
    hipLaunchKernelGGL(scatter_kernel, dim3(nbs), dim3(SC_TPB),  0, stream, points, npts, cursor, recs);

    hipLaunchKernelGGL(trilerp_brick_kernel, dim3(NBKT), dim3(BTPB), 0, stream,
                       data, links, recs, cnt, cursor, out);
}